// Round 14
// baseline (3584.583 us; speedup 1.0000x reference)
//
#include <hip/hip_runtime.h>
#include <stdint.h>

#define B 64
#define S 512
#define E 512
#define H 1024
#define NCLS 4

typedef __attribute__((ext_vector_type(8))) short short8;
typedef __attribute__((ext_vector_type(4))) float f32x4;

__device__ __forceinline__ unsigned short f32_to_bf16(float f) {
    unsigned int x = __float_as_uint(f);
    unsigned int r = (x + 0x7fffu + ((x >> 16) & 1u)) >> 16;   // RNE
    return (unsigned short)r;
}
__device__ __forceinline__ float bf16_to_f32(unsigned short u) {
    return __uint_as_float(((unsigned int)u) << 16);
}

// write-through store (L1+L2 bypass -> MALL coherence point). PROVEN R2-R13.
__device__ __forceinline__ void store_sc4u(unsigned int* p, unsigned int v) {
    asm volatile("global_store_dword %0, %1, off sc0 sc1"
                 :: "v"(p), "v"(v) : "memory");
}

// ---------------------------------------------------------------------------
// K1: wx[s][b][j] = sum_k emb[x[b*S+s]][k] * W[j][k] + b_w[j], stored bf16.
// (unchanged; ~57 us)
// ---------------------------------------------------------------------------
#define K1_LDA 40

__global__ __launch_bounds__(256) void k_wx_gemm(
    const int* __restrict__ x, const float* __restrict__ emb,
    const float* __restrict__ W, const float* __restrict__ bw,
    unsigned short* __restrict__ wx)
{
    __shared__ unsigned short Asub[128 * K1_LDA];
    __shared__ unsigned short Bsub[128 * K1_LDA];

    const int t  = threadIdx.x;
    const int mt = blockIdx.x;
    const int nt = blockIdx.y;
    const int i0 = mt * 128;
    const int j0 = nt * 128;

    const int r  = t >> 1;
    const int kh = (t & 1) * 16;
    const int tok = x[i0 + r];
    const float* arow = emb + (size_t)tok * E;
    const float* brow = W + (size_t)(j0 + r) * E;

    const int lane = t & 63;
    const int w    = t >> 6;
    const int wm   = (w >> 1) * 64;
    const int wn   = (w & 1) * 64;
    const int fr   = lane & 15;
    const int kg   = lane >> 4;

    f32x4 acc[4][4] = {};

    for (int kt = 0; kt < E; kt += 32) {
        __syncthreads();
        {
            union { unsigned short us[8]; uint4 v; } p;
            const float* srcA = arow + kt + kh;
            #pragma unroll
            for (int i = 0; i < 8; ++i) p.us[i] = f32_to_bf16(srcA[i]);
            *(uint4*)&Asub[r * K1_LDA + kh] = p.v;
            #pragma unroll
            for (int i = 0; i < 8; ++i) p.us[i] = f32_to_bf16(srcA[8 + i]);
            *(uint4*)&Asub[r * K1_LDA + kh + 8] = p.v;
            const float* srcB = brow + kt + kh;
            #pragma unroll
            for (int i = 0; i < 8; ++i) p.us[i] = f32_to_bf16(srcB[i]);
            *(uint4*)&Bsub[r * K1_LDA + kh] = p.v;
            #pragma unroll
            for (int i = 0; i < 8; ++i) p.us[i] = f32_to_bf16(srcB[8 + i]);
            *(uint4*)&Bsub[r * K1_LDA + kh + 8] = p.v;
        }
        __syncthreads();

        short8 a[4], b[4];
        #pragma unroll
        for (int mi = 0; mi < 4; ++mi)
            a[mi] = *(const short8*)&Asub[(wm + mi * 16 + fr) * K1_LDA + kg * 8];
        #pragma unroll
        for (int ni = 0; ni < 4; ++ni)
            b[ni] = *(const short8*)&Bsub[(wn + ni * 16 + fr) * K1_LDA + kg * 8];
        #pragma unroll
        for (int mi = 0; mi < 4; ++mi)
            #pragma unroll
            for (int ni = 0; ni < 4; ++ni)
                acc[mi][ni] = __builtin_amdgcn_mfma_f32_16x16x32_bf16(
                                  a[mi], b[ni], acc[mi][ni], 0, 0, 0);
    }

    float bwv[4];
    #pragma unroll
    for (int ni = 0; ni < 4; ++ni) bwv[ni] = bw[j0 + wn + ni * 16 + fr];
    #pragma unroll
    for (int mi = 0; mi < 4; ++mi) {
        #pragma unroll
        for (int ni = 0; ni < 4; ++ni) {
            const int gn = j0 + wn + ni * 16 + fr;
            #pragma unroll
            for (int rr = 0; rr < 4; ++rr) {
                const int gm = i0 + wm + mi * 16 + kg * 4 + rr;
                const int bb = gm >> 9;
                const int ss = gm & 511;
                wx[(size_t)(ss * B + bb) * H + gn] =
                    f32_to_bf16(acc[mi][ni][rr] + bwv[ni]);
            }
        }
    }
}

// ---------------------------------------------------------------------------
// K2: persistent recurrence = R13 (1557us measured) + PUBLISHER/CONSUMER
// ROLE ALTERNATION: zero __syncthreads in the loop.
//  - Every wave each step: poll(8 producers x 2 pub-waves = 16 flags) ->
//    stage own k-chunk -> MFMA -> redC[ts&1] partial -> LDS cnt[ts&1]++.
//  - Publisher pair (waves {2*(ts&1),+1}) spins cnt==4, sums all partials,
//    tanh, publishes ALL 256 outputs (2/lane), drains, sets 2 flags
//    fl[(ts&1)*64 + m*2 + pw]. Other pair proceeds to next step's poll,
//    overlapping the publish tail (skew absorption).
//  - Safety: redC dbuf + transitive flag chain (see round theory); H-plane
//    LDS windows are wave-private; role branch is wave-uniform.
//  - LDS: 64K U + 16K Hhi + 16K Hlo + 8K redC + cnt = ~104.5 KB (1 wg/CU).
// ---------------------------------------------------------------------------
__global__ __launch_bounds__(256) void k_rnn(
    const unsigned short* __restrict__ wx, const float* __restrict__ U,
    const float* __restrict__ Vw, const float* __restrict__ bv,
    unsigned int* __restrict__ hbuf, unsigned int* __restrict__ flags,
    float* __restrict__ out)
{
    __shared__ __align__(16) unsigned short Uhi[32 * 1024];   // 64 KB
    __shared__ __align__(16) unsigned int Hh32[8 * 512];      // 16 KB
    __shared__ __align__(16) unsigned int Hl32[8 * 512];      // 16 KB
    __shared__ __align__(16) float redC[2][1024];             //  8 KB
    __shared__ unsigned int cnt[2];

    const int t   = threadIdx.x;
    const int g   = blockIdx.x & 7;      // group: batches [8g, 8g+8)
    const int m   = blockIdx.x >> 3;     // member: j rows [32m, 32m+32)
    const int j0  = m * 32;
    const int bg0 = g * 8;

    // ---- stage U -> bf16 plane, swizzled (byte ^= (row&7)<<4) ----
    for (int rr = 0; rr < 32; ++rr) {
        f32x4 v = *(const f32x4*)(U + (size_t)(j0 + rr) * H + t * 4);
        uint2 hwd;
        hwd.x = f32_to_bf16(v[0]) | ((unsigned)f32_to_bf16(v[1]) << 16);
        hwd.y = f32_to_bf16(v[2]) | ((unsigned)f32_to_bf16(v[3]) << 16);
        const int byteoff = (rr * 2048 + t * 8) ^ ((rr & 7) << 4);
        *(uint2*)((char*)Uhi + byteoff) = hwd;
    }
    if (t < 2) cnt[t] = 0u;

    // role constants
    const int lane  = t & 63;
    const int w     = t >> 6;            // wave id = K-chunk (256 k each)
    const int fr    = lane & 15;
    const int kg    = lane >> 4;         // 0..3
    const int kbase = w * 256;
    const int abrow = fr & 7;            // A (h) row: batches 8-15 dup 0-7
    const int pw    = w & 1;             // publisher slot within pair
    // my 2 publisher outputs (o == ob*32+oj by construction)
    const int o0  = pw * 128 + lane,  o1 = o0 + 64;
    const int ob0 = o0 >> 5, oj0 = o0 & 31;
    const int ob1 = o1 >> 5, oj1 = o1 & 31;

    unsigned int* fl = flags + g * 128;  // [slot_parity 2][m 32][pw 2]

    float wxv0 = 0.f, wxv1 = 0.f;
    if ((w >> 1) == 0) {                 // publishers of step 0
        wxv0 = bf16_to_f32(wx[(size_t)(bg0 + ob0) * H + j0 + oj0]);
        wxv1 = bf16_to_f32(wx[(size_t)(bg0 + ob1) * H + j0 + oj1]);
    }

    __syncthreads();                     // U + cnt ready (last wg barrier)

    for (int ts = 0; ts < S; ++ts) {
        const unsigned int* hr = hbuf + (ts & 1) * (B * H);
        unsigned int*       hw = hbuf + ((ts + 1) & 1) * (B * H);
        const bool pub  = ((w >> 1) == (ts & 1));
        const int  sin  = (ts + 1) & 1;  // incoming flag slot parity
        const int  spub = ts & 1;        // outgoing flag slot / redC / cnt

        // ---- poll: 8 producers x 2 publisher-waves = 16 contiguous flags --
        {
            const unsigned int* fp = fl + sin * 64 + 16 * w + (lane & 15);
            unsigned int fv;
            do {
                fv = __hip_atomic_load(fp, __ATOMIC_RELAXED,
                                       __HIP_MEMORY_SCOPE_AGENT);
            } while (!__all((int)(fv >= (unsigned)ts)));
        }

        // wx prefetch for next step (I publish at ts+1 iff !pub now)
        float wn0 = 0.f, wn1 = 0.f;
        if (!pub && ts + 1 < S) {
            wn0 = bf16_to_f32(wx[(size_t)((ts + 1) * B + bg0 + ob0) * H + j0 + oj0]);
            wn1 = bf16_to_f32(wx[(size_t)((ts + 1) * B + bg0 + ob1) * H + j0 + oj1]);
        }

        // ---- wave-private stage: k-chunk [256w,256w+256) x 8 batches ----
        {
            const unsigned long long* hb64 = (const unsigned long long*)hr;
            unsigned long long vv[16];
            #pragma unroll
            for (int i = 0; i < 16; ++i) {
                const int li = lane + 64 * i;
                const int b = li >> 7, col = li & 127;
                vv[i] = __hip_atomic_load(
                    hb64 + (size_t)(bg0 + b) * 512 + w * 128 + col,
                    __ATOMIC_RELAXED, __HIP_MEMORY_SCOPE_AGENT);
            }
            #pragma unroll
            for (int i = 0; i < 16; ++i) {
                const int li = lane + 64 * i;
                const int b = li >> 7;
                const int k2 = w * 128 + (li & 127);
                const unsigned int v0 = (unsigned int)vv[i];
                const unsigned int v1 = (unsigned int)(vv[i] >> 32);
                const int idx = (b * 512 + k2) ^ (b << 2);
                Hh32[idx] = (v0 >> 16) | (v1 & 0xffff0000u);
                Hl32[idx] = (v0 & 0xffffu) | (v1 << 16);
            }
        }

        // ---- MFMA: C[16b x 32j] over my k-chunk, 2 split terms ----
        f32x4 acc0 = {}, acc1 = {};
        #pragma unroll
        for (int kk = 0; kk < 8; ++kk) {
            const int k  = kbase + kk * 32 + kg * 8;
            const int ab = (abrow * 2048 + k * 2) ^ (abrow << 4);
            const short8 ahi = *(const short8*)((const char*)Hh32 + ab);
            const short8 alo = *(const short8*)((const char*)Hl32 + ab);
            const int b0 = (fr * 2048 + k * 2) ^ ((fr & 7) << 4);
            const int b1 = ((16 + fr) * 2048 + k * 2) ^ ((fr & 7) << 4);
            const short8 bh0 = *(const short8*)((const char*)Uhi + b0);
            const short8 bh1 = *(const short8*)((const char*)Uhi + b1);
            acc0 = __builtin_amdgcn_mfma_f32_16x16x32_bf16(ahi, bh0, acc0, 0, 0, 0);
            acc0 = __builtin_amdgcn_mfma_f32_16x16x32_bf16(alo, bh0, acc0, 0, 0, 0);
            acc1 = __builtin_amdgcn_mfma_f32_16x16x32_bf16(ahi, bh1, acc1, 0, 0, 0);
            acc1 = __builtin_amdgcn_mfma_f32_16x16x32_bf16(alo, bh1, acc1, 0, 0, 0);
        }

        // ---- per-wave partial-C into redC[spub], then count in ----
        float* rc = redC[spub];
        if (kg < 2) {
            #pragma unroll
            for (int rr = 0; rr < 4; ++rr) {
                const int mb = kg * 4 + rr;          // batch row 0..7
                rc[w * 256 + mb * 32 + fr]      = acc0[rr];
                rc[w * 256 + mb * 32 + 16 + fr] = acc1[rr];
            }
        }
        asm volatile("s_waitcnt lgkmcnt(0)" ::: "memory");  // redC writes done
        if (lane == 0)
            __hip_atomic_fetch_add(&cnt[spub], 1u, __ATOMIC_RELEASE,
                                   __HIP_MEMORY_SCOPE_WORKGROUP);

        if (pub) {
            // wait for all 4 waves' partials (cumulative target)
            const unsigned int tgt = 4u * ((unsigned)(ts >> 1) + 1u);
            while (__hip_atomic_load(&cnt[spub], __ATOMIC_ACQUIRE,
                                     __HIP_MEMORY_SCOPE_WORKGROUP) < tgt) {}

            float s0 = rc[o0] + rc[256 + o0] + rc[512 + o0] + rc[768 + o0];
            float s1 = rc[o1] + rc[256 + o1] + rc[512 + o1] + rc[768 + o1];
            float p0 = fminf(fmaxf(wxv0 + s0, -15.f), 15.f);
            float p1 = fminf(fmaxf(wxv1 + s1, -15.f), 15.f);
            const float e0 = __expf(2.0f * p0);
            const float e1 = __expf(2.0f * p1);
            const float h0 = 1.0f - 2.0f / (e0 + 1.0f);
            const float h1 = 1.0f - 2.0f / (e1 + 1.0f);
            const unsigned short h0b = f32_to_bf16(h0);
            const unsigned short l0b = f32_to_bf16(h0 - bf16_to_f32(h0b));
            const unsigned short h1b = f32_to_bf16(h1);
            const unsigned short l1b = f32_to_bf16(h1 - bf16_to_f32(h1b));
            store_sc4u(hw + (size_t)(bg0 + ob0) * H + j0 + oj0,
                       ((unsigned int)h0b << 16) | l0b);
            store_sc4u(hw + (size_t)(bg0 + ob1) * H + j0 + oj1,
                       ((unsigned int)h1b << 16) | l1b);
            asm volatile("s_waitcnt vmcnt(0)" ::: "memory");   // h at MALL
            if (lane == 0)
                __hip_atomic_store(&fl[spub * 64 + m * 2 + pw],
                                   (unsigned)(ts + 1), __ATOMIC_RELAXED,
                                   __HIP_MEMORY_SCOPE_AGENT);
        } else {
            wxv0 = wn0; wxv1 = wn1;      // I publish next step
        }
    }

    // ---- final projection: out[b][c] = h_final[b] . V[c] + bv[c] ----
    if (m == 0) {
        if (t < 64)   // step-511 publishers wrote slot parity 1
            while (__hip_atomic_load(&fl[64 + t], __ATOMIC_RELAXED,
                                     __HIP_MEMORY_SCOPE_AGENT) < (unsigned)S) {}
        __syncthreads();
        const unsigned int* hf = hbuf;   // S even -> final state in buf0
        const int o = t & 31, part = t >> 5;
        const int pb = o >> 2, c = o & 3;
        const unsigned long long* hrow =
            (const unsigned long long*)(hf + (size_t)(bg0 + pb) * H) + part * 64;
        const float* vrow = Vw + (size_t)c * H + part * 128;
        float partial = 0.f;
        for (int q = 0; q < 64; ++q) {
            unsigned long long vvq = __hip_atomic_load(hrow + q, __ATOMIC_RELAXED,
                                                       __HIP_MEMORY_SCOPE_AGENT);
            const unsigned int v0 = (unsigned int)vvq;
            const unsigned int v1 = (unsigned int)(vvq >> 32);
            const float h0 = bf16_to_f32((unsigned short)(v0 >> 16))
                           + bf16_to_f32((unsigned short)(v0 & 0xffffu));
            const float h1 = bf16_to_f32((unsigned short)(v1 >> 16))
                           + bf16_to_f32((unsigned short)(v1 & 0xffffu));
            partial += h0 * vrow[2 * q] + h1 * vrow[2 * q + 1];
        }
        __syncthreads();
        redC[0][part * 32 + o] = partial;
        __syncthreads();
        if (t < 32) {
            float sv = 0.f;
            #pragma unroll
            for (int pq = 0; pq < 8; ++pq) sv += redC[0][pq * 32 + t];
            out[(bg0 + (t >> 2)) * NCLS + (t & 3)] = sv + bv[t & 3];
        }
    }
}

// ---------------------------------------------------------------------------
extern "C" void kernel_launch(void* const* d_in, const int* in_sizes, int n_in,
                              void* d_out, int out_size, void* d_ws, size_t ws_size,
                              hipStream_t stream)
{
    const int*   x   = (const int*)d_in[0];
    const float* emb = (const float*)d_in[1];
    const float* W   = (const float*)d_in[2];
    const float* bw  = (const float*)d_in[3];
    const float* U   = (const float*)d_in[4];
    const float* V   = (const float*)d_in[5];
    const float* bv  = (const float*)d_in[6];
    float* out = (float*)d_out;

    unsigned short* wx = (unsigned short*)d_ws;
    const size_t WX_BYTES = (size_t)S * B * H * sizeof(unsigned short); // 64 MiB
    unsigned int* hbuf = (unsigned int*)((char*)d_ws + WX_BYTES);
    const size_t HB_BYTES = (size_t)2 * B * H * sizeof(unsigned int);   // 512 KiB
    unsigned int* flags = (unsigned int*)((char*)d_ws + WX_BYTES + HB_BYTES);

    // zero h double-buffer (h0 = 0) + 8x128 [parity][member][pw] flags
    hipMemsetAsync((char*)d_ws + WX_BYTES, 0, HB_BYTES + 8192, stream);

    hipLaunchKernelGGL(k_wx_gemm, dim3(256, 8), dim3(256), 0, stream,
                       x, emb, W, bw, wx);
    hipLaunchKernelGGL(k_rnn, dim3(256), dim3(256), 0, stream,
                       wx, U, V, bv, hbuf, flags, out);
}

// Round 15
// 1553.975 us; speedup vs baseline: 2.3067x; 2.3067x over previous
//
#include <hip/hip_runtime.h>
#include <stdint.h>

#define B 64
#define S 512
#define E 512
#define H 1024
#define NCLS 4

typedef __attribute__((ext_vector_type(8))) short short8;
typedef __attribute__((ext_vector_type(4))) float f32x4;

__device__ __forceinline__ unsigned short f32_to_bf16(float f) {
    unsigned int x = __float_as_uint(f);
    unsigned int r = (x + 0x7fffu + ((x >> 16) & 1u)) >> 16;   // RNE
    return (unsigned short)r;
}
__device__ __forceinline__ float bf16_to_f32(unsigned short u) {
    return __uint_as_float(((unsigned int)u) << 16);
}

// write-through store (L1+L2 bypass -> MALL coherence point). PROVEN R2-R13.
__device__ __forceinline__ void store_sc4u(unsigned int* p, unsigned int v) {
    asm volatile("global_store_dword %0, %1, off sc0 sc1"
                 :: "v"(p), "v"(v) : "memory");
}

// ---------------------------------------------------------------------------
// K1: wx[s][b][j] = sum_k emb[x[b*S+s]][k] * W[j][k] + b_w[j], stored bf16.
// (unchanged; ~57 us)
// ---------------------------------------------------------------------------
#define K1_LDA 40

__global__ __launch_bounds__(256) void k_wx_gemm(
    const int* __restrict__ x, const float* __restrict__ emb,
    const float* __restrict__ W, const float* __restrict__ bw,
    unsigned short* __restrict__ wx)
{
    __shared__ unsigned short Asub[128 * K1_LDA];
    __shared__ unsigned short Bsub[128 * K1_LDA];

    const int t  = threadIdx.x;
    const int mt = blockIdx.x;
    const int nt = blockIdx.y;
    const int i0 = mt * 128;
    const int j0 = nt * 128;

    const int r  = t >> 1;
    const int kh = (t & 1) * 16;
    const int tok = x[i0 + r];
    const float* arow = emb + (size_t)tok * E;
    const float* brow = W + (size_t)(j0 + r) * E;

    const int lane = t & 63;
    const int w    = t >> 6;
    const int wm   = (w >> 1) * 64;
    const int wn   = (w & 1) * 64;
    const int fr   = lane & 15;
    const int kg   = lane >> 4;

    f32x4 acc[4][4] = {};

    for (int kt = 0; kt < E; kt += 32) {
        __syncthreads();
        {
            union { unsigned short us[8]; uint4 v; } p;
            const float* srcA = arow + kt + kh;
            #pragma unroll
            for (int i = 0; i < 8; ++i) p.us[i] = f32_to_bf16(srcA[i]);
            *(uint4*)&Asub[r * K1_LDA + kh] = p.v;
            #pragma unroll
            for (int i = 0; i < 8; ++i) p.us[i] = f32_to_bf16(srcA[8 + i]);
            *(uint4*)&Asub[r * K1_LDA + kh + 8] = p.v;
            const float* srcB = brow + kt + kh;
            #pragma unroll
            for (int i = 0; i < 8; ++i) p.us[i] = f32_to_bf16(srcB[i]);
            *(uint4*)&Bsub[r * K1_LDA + kh] = p.v;
            #pragma unroll
            for (int i = 0; i < 8; ++i) p.us[i] = f32_to_bf16(srcB[8 + i]);
            *(uint4*)&Bsub[r * K1_LDA + kh + 8] = p.v;
        }
        __syncthreads();

        short8 a[4], b[4];
        #pragma unroll
        for (int mi = 0; mi < 4; ++mi)
            a[mi] = *(const short8*)&Asub[(wm + mi * 16 + fr) * K1_LDA + kg * 8];
        #pragma unroll
        for (int ni = 0; ni < 4; ++ni)
            b[ni] = *(const short8*)&Bsub[(wn + ni * 16 + fr) * K1_LDA + kg * 8];
        #pragma unroll
        for (int mi = 0; mi < 4; ++mi)
            #pragma unroll
            for (int ni = 0; ni < 4; ++ni)
                acc[mi][ni] = __builtin_amdgcn_mfma_f32_16x16x32_bf16(
                                  a[mi], b[ni], acc[mi][ni], 0, 0, 0);
    }

    float bwv[4];
    #pragma unroll
    for (int ni = 0; ni < 4; ++ni) bwv[ni] = bw[j0 + wn + ni * 16 + fr];
    #pragma unroll
    for (int mi = 0; mi < 4; ++mi) {
        #pragma unroll
        for (int ni = 0; ni < 4; ++ni) {
            const int gn = j0 + wn + ni * 16 + fr;
            #pragma unroll
            for (int rr = 0; rr < 4; ++rr) {
                const int gm = i0 + wm + mi * 16 + kg * 4 + rr;
                const int bb = gm >> 9;
                const int ss = gm & 511;
                wx[(size_t)(ss * B + bb) * H + gn] =
                    f32_to_bf16(acc[mi][ni][rr] + bwv[ni]);
            }
        }
    }
}

// ---------------------------------------------------------------------------
// K2: persistent recurrence — FINAL = R13 (measured 1557us, best).
//  - 8 groups x 32 members (1 wg/CU). Member m: j rows [32m, 32m+32).
//  - U in LDS as ONE bf16 plane, XOR-swizzled (byte ^= (row&7)<<4).
//  - h packed (bf16hi<<16)|bf16lo via MALL (sc0 sc1 stores / agent loads).
//  - PER-(MEMBER,WAVE) FLAGS: each wave drains its own h stores (wave-local
//    vmcnt) and sets flag[m*4+w]; consumer wave w polls its 8 producers x 4
//    waves = 32 contiguous flags. One barrier per step (barD, redC dbuf).
//  - WAR: flag[Y][w']>=ts => Y passed barD(ts-1) => all Y waves finished
//    reading buf[(ts-1)&1]. X writes h(ts+1) after barD(ts) which joins
//    polls covering all 32 members x 4 waves.
//  - LDS: 64K U + 16K Hhi + 16K Hlo + 8K redC = 104 KB (1 wg/CU).
// ---------------------------------------------------------------------------
__global__ __launch_bounds__(256) void k_rnn(
    const unsigned short* __restrict__ wx, const float* __restrict__ U,
    const float* __restrict__ Vw, const float* __restrict__ bv,
    unsigned int* __restrict__ hbuf, unsigned int* __restrict__ flags,
    float* __restrict__ out)
{
    __shared__ __align__(16) unsigned short Uhi[32 * 1024];   // 64 KB
    __shared__ __align__(16) unsigned int Hh32[8 * 512];      // 16 KB
    __shared__ __align__(16) unsigned int Hl32[8 * 512];      // 16 KB
    __shared__ __align__(16) float redC[2][1024];             //  8 KB

    const int t   = threadIdx.x;
    const int g   = blockIdx.x & 7;      // group: batches [8g, 8g+8)
    const int m   = blockIdx.x >> 3;     // member: j rows [32m, 32m+32)
    const int j0  = m * 32;
    const int bg0 = g * 8;

    // ---- stage U -> bf16 plane, swizzled (byte ^= (row&7)<<4) ----
    for (int rr = 0; rr < 32; ++rr) {
        f32x4 v = *(const f32x4*)(U + (size_t)(j0 + rr) * H + t * 4);
        uint2 hwd;
        hwd.x = f32_to_bf16(v[0]) | ((unsigned)f32_to_bf16(v[1]) << 16);
        hwd.y = f32_to_bf16(v[2]) | ((unsigned)f32_to_bf16(v[3]) << 16);
        const int byteoff = (rr * 2048 + t * 8) ^ ((rr & 7) << 4);
        *(uint2*)((char*)Uhi + byteoff) = hwd;
    }

    // role constants
    const int lane  = t & 63;
    const int w     = t >> 6;            // wave id = K-chunk (256 k each)
    const int fr    = lane & 15;
    const int kg    = lane >> 4;         // 0..3
    const int kbase = w * 256;
    const int abrow = fr & 7;            // A (h) row: batches 8-15 dup 0-7
    const int ob    = t >> 5;            // output batch 0..7
    const int oj    = t & 31;            // output j local 0..31

    unsigned int* fl = flags + g * 128;  // [member][wave] flags

    float wxv = bf16_to_f32(wx[(size_t)(bg0 + ob) * H + j0 + oj]);

    __syncthreads();                     // U resident

    for (int ts = 0; ts < S; ++ts) {
        const unsigned int* hr = hbuf + (ts & 1) * (B * H);
        unsigned int*       hw = hbuf + ((ts + 1) & 1) * (B * H);

        // prefetch next step's wx (h-independent, cached) before the poll
        float wx_next = 0.f;
        if (ts + 1 < S)
            wx_next = bf16_to_f32(wx[(size_t)((ts + 1) * B + bg0 + ob) * H + j0 + oj]);

        // ---- wave-private poll: 8 producers x 4 waves = 32 contiguous flags
        {
            const unsigned int* fp = fl + w * 32 + (lane & 31);
            unsigned int fv;
            do {
                fv = __hip_atomic_load(fp, __ATOMIC_RELAXED,
                                       __HIP_MEMORY_SCOPE_AGENT);
            } while (!__all((int)(fv >= (unsigned)ts)));
        }

        // ---- wave-private stage: k-chunk [256w,256w+256) x 8 batches ----
        // lane covers 16 u64 words: li = lane + 64*i -> b = li>>7, col = li&127
        {
            const unsigned long long* hb64 = (const unsigned long long*)hr;
            unsigned long long vv[16];
            #pragma unroll
            for (int i = 0; i < 16; ++i) {
                const int li = lane + 64 * i;
                const int b = li >> 7, col = li & 127;
                vv[i] = __hip_atomic_load(
                    hb64 + (size_t)(bg0 + b) * 512 + w * 128 + col,
                    __ATOMIC_RELAXED, __HIP_MEMORY_SCOPE_AGENT);
            }
            #pragma unroll
            for (int i = 0; i < 16; ++i) {
                const int li = lane + 64 * i;
                const int b = li >> 7;
                const int k2 = w * 128 + (li & 127);
                const unsigned int v0 = (unsigned int)vv[i];
                const unsigned int v1 = (unsigned int)(vv[i] >> 32);
                const int idx = (b * 512 + k2) ^ (b << 2);
                Hh32[idx] = (v0 >> 16) | (v1 & 0xffff0000u);
                Hl32[idx] = (v0 & 0xffffu) | (v1 << 16);
            }
        }
        // no barrier: wave w's MFMA reads only its own staged k-chunk

        // ---- MFMA: C[16b x 32j] over my k-chunk, 2 split terms ----
        f32x4 acc0 = {}, acc1 = {};
        #pragma unroll
        for (int kk = 0; kk < 8; ++kk) {
            const int k  = kbase + kk * 32 + kg * 8;
            const int ab = (abrow * 2048 + k * 2) ^ (abrow << 4);
            const short8 ahi = *(const short8*)((const char*)Hh32 + ab);
            const short8 alo = *(const short8*)((const char*)Hl32 + ab);
            const int b0 = (fr * 2048 + k * 2) ^ ((fr & 7) << 4);
            const int b1 = ((16 + fr) * 2048 + k * 2) ^ ((fr & 7) << 4);
            const short8 bh0 = *(const short8*)((const char*)Uhi + b0);
            const short8 bh1 = *(const short8*)((const char*)Uhi + b1);
            acc0 = __builtin_amdgcn_mfma_f32_16x16x32_bf16(ahi, bh0, acc0, 0, 0, 0);
            acc0 = __builtin_amdgcn_mfma_f32_16x16x32_bf16(alo, bh0, acc0, 0, 0, 0);
            acc1 = __builtin_amdgcn_mfma_f32_16x16x32_bf16(ahi, bh1, acc1, 0, 0, 0);
            acc1 = __builtin_amdgcn_mfma_f32_16x16x32_bf16(alo, bh1, acc1, 0, 0, 0);
        }

        // ---- per-wave partial-C into double-buffered redC ----
        float* rc = redC[ts & 1];
        if (kg < 2) {
            #pragma unroll
            for (int rr = 0; rr < 4; ++rr) {
                const int mb = kg * 4 + rr;          // batch row 0..7
                rc[w * 256 + mb * 32 + fr]      = acc0[rr];
                rc[w * 256 + mb * 32 + 16 + fr] = acc1[rr];
            }
        }
        __syncthreads();                 // barD: redC complete (the one barrier)

        float sum = rc[      ob * 32 + oj] + rc[256 + ob * 32 + oj]
                  + rc[512 + ob * 32 + oj] + rc[768 + ob * 32 + oj];

        float p = wxv + sum;
        p = fminf(fmaxf(p, -15.f), 15.f);
        const float e  = __expf(2.0f * p);
        const float hv = 1.0f - 2.0f / (e + 1.0f);

        // pack hi|lo, publish, wave-local drain, per-wave flag
        const unsigned short hib = f32_to_bf16(hv);
        const unsigned short lob = f32_to_bf16(hv - bf16_to_f32(hib));
        store_sc4u(hw + (size_t)(bg0 + ob) * H + j0 + oj,
                   ((unsigned int)hib << 16) | lob);
        asm volatile("s_waitcnt vmcnt(0)" ::: "memory");   // this wave's h at MALL
        if (lane == 0)
            __hip_atomic_store(&fl[m * 4 + w], (unsigned)(ts + 1),
                               __ATOMIC_RELAXED, __HIP_MEMORY_SCOPE_AGENT);
        wxv = wx_next;
    }

    // ---- final projection: out[b][c] = h_final[b] . V[c] + bv[c] ----
    if (m == 0) {
        if (t < 128)
            while (__hip_atomic_load(&fl[t], __ATOMIC_RELAXED,
                                     __HIP_MEMORY_SCOPE_AGENT) < (unsigned)S) {}
        __syncthreads();
        const unsigned int* hf = hbuf;   // S even -> final state in buf0
        const int o = t & 31, part = t >> 5;
        const int pb = o >> 2, c = o & 3;
        const unsigned long long* hrow =
            (const unsigned long long*)(hf + (size_t)(bg0 + pb) * H) + part * 64;
        const float* vrow = Vw + (size_t)c * H + part * 128;
        float partial = 0.f;
        for (int q = 0; q < 64; ++q) {
            unsigned long long vvq = __hip_atomic_load(hrow + q, __ATOMIC_RELAXED,
                                                       __HIP_MEMORY_SCOPE_AGENT);
            const unsigned int v0 = (unsigned int)vvq;
            const unsigned int v1 = (unsigned int)(vvq >> 32);
            const float h0 = bf16_to_f32((unsigned short)(v0 >> 16))
                           + bf16_to_f32((unsigned short)(v0 & 0xffffu));
            const float h1 = bf16_to_f32((unsigned short)(v1 >> 16))
                           + bf16_to_f32((unsigned short)(v1 & 0xffffu));
            partial += h0 * vrow[2 * q] + h1 * vrow[2 * q + 1];
        }
        __syncthreads();
        redC[0][part * 32 + o] = partial;
        __syncthreads();
        if (t < 32) {
            float sv = 0.f;
            #pragma unroll
            for (int pq = 0; pq < 8; ++pq) sv += redC[0][pq * 32 + t];
            out[(bg0 + (t >> 2)) * NCLS + (t & 3)] = sv + bv[t & 3];
        }
    }
}

// ---------------------------------------------------------------------------
extern "C" void kernel_launch(void* const* d_in, const int* in_sizes, int n_in,
                              void* d_out, int out_size, void* d_ws, size_t ws_size,
                              hipStream_t stream)
{
    const int*   x   = (const int*)d_in[0];
    const float* emb = (const float*)d_in[1];
    const float* W   = (const float*)d_in[2];
    const float* bw  = (const float*)d_in[3];
    const float* U   = (const float*)d_in[4];
    const float* V   = (const float*)d_in[5];
    const float* bv  = (const float*)d_in[6];
    float* out = (float*)d_out;

    unsigned short* wx = (unsigned short*)d_ws;
    const size_t WX_BYTES = (size_t)S * B * H * sizeof(unsigned short); // 64 MiB
    unsigned int* hbuf = (unsigned int*)((char*)d_ws + WX_BYTES);
    const size_t HB_BYTES = (size_t)2 * B * H * sizeof(unsigned int);   // 512 KiB
    unsigned int* flags = (unsigned int*)((char*)d_ws + WX_BYTES + HB_BYTES);

    // zero h double-buffer (h0 = 0) + 8x128 per-(member,wave) flags
    hipMemsetAsync((char*)d_ws + WX_BYTES, 0, HB_BYTES + 8192, stream);

    hipLaunchKernelGGL(k_wx_gemm, dim3(256, 8), dim3(256), 0, stream,
                       x, emb, W, bw, wx);
    hipLaunchKernelGGL(k_rnn, dim3(256), dim3(256), 0, stream,
                       wx, U, V, bv, hbuf, flags, out);
}